// Round 9
// baseline (14237.727 us; speedup 1.0000x reference)
//
#include <hip/hip_runtime.h>

#define SEQ   1024
#define DIN   64
#define NHID  256
#define NBLK  64
#define NTHR  512

typedef _Float16 f16x8 __attribute__((ext_vector_type(8)));
typedef float    f32x4 __attribute__((ext_vector_type(4)));
typedef unsigned long long u64;

#define MFMA16(a,b,c) __builtin_amdgcn_mfma_f32_16x16x32_f16((a),(b),(c),0,0,0)
#define ALOAD(p)    __hip_atomic_load((p), __ATOMIC_RELAXED, __HIP_MEMORY_SCOPE_AGENT)
#define ASTORE(p,v) __hip_atomic_store((p),(v), __ATOMIC_RELAXED, __HIP_MEMORY_SCOPE_AGENT)

// F-path: sc0-only = L1-bypass, lands/reads the XCD's write-back L2. Fast but
// only visible within one XCD -> NEVER trusted alone (S-path is the guarantee).
#define LD_F(d,p) asm volatile("global_load_dwordx2 %0, %1, off sc0" \
                               : "=v"(d) : "v"(p) : "memory")
#define ST_F(p,v) asm volatile("global_store_dwordx2 %0, %1, off sc0" \
                               :: "v"(p), "v"(v) : "memory")
#define WAIT3(a,b,c) do{ \
  asm volatile("s_waitcnt vmcnt(0)" : "+v"(a),"+v"(b),"+v"(c) :: "memory"); \
  __builtin_amdgcn_sched_barrier(0); }while(0)

__device__ __forceinline__ float sigm(float v){
  return __builtin_amdgcn_rcpf(1.f + __expf(-v));
}
__device__ __forceinline__ float tanh_f(float v){
  return 1.f - 2.f*__builtin_amdgcn_rcpf(__expf(2.f*v)+1.f);
}

__device__ __forceinline__ f16x8 cvt8(f32x4 a, f32x4 b){
  f16x8 r;
  r[0]=(_Float16)a[0]; r[1]=(_Float16)a[1]; r[2]=(_Float16)a[2]; r[3]=(_Float16)a[3];
  r[4]=(_Float16)b[0]; r[5]=(_Float16)b[1]; r[6]=(_Float16)b[2]; r[7]=(_Float16)b[3];
  return r;
}

union U32H2 { unsigned int u; _Float16 h[2]; unsigned short us[2]; };

// 64 blocks = 16 groups (16 batch rows) x 4 members (64 hidden cols).
// R4-proven tagged-u64 exchange (tag s+1, parity s&1, memset-0 per launch)
// published BOTH agent-scope (S, guaranteed) and sc0 L2-local (F, fast iff
// partners share the XCD). fastOK learned once at s==0 via bounded F-probe;
// fast spin keeps an S backstop every 64 rounds => deadlock impossible.
__global__ void __launch_bounds__(NTHR, 2)
lstm_seq(const float* __restrict__ x, const float* __restrict__ h0,
         const float* __restrict__ c0, const float* __restrict__ Wi,
         const float* __restrict__ bi, const float* __restrict__ Wh,
         const float* __restrict__ bh, const float* __restrict__ Wcls,
         const float* __restrict__ bcls,
         u64* __restrict__ slices, u64* __restrict__ fastb,
         float* __restrict__ out)
{
  __shared__ __align__(16) unsigned int hbuf[2][16*128]; // word ^= (b&7)<<2

  const int bid = blockIdx.x;
  const int grp = bid & 15;          // batch group (16 rows)
  const int q   = bid >> 4;          // hidden quarter 0..3
  const int tid = threadIdx.x;
  const int w   = tid >> 6;          // wave 0..7
  const int l   = tid & 63;
  const int l15 = l & 15;
  const int lhi = l >> 4;

  // ---- A-frags: weights, register-resident f16, permuted rows ----
  // m-tile mt = w*2+t ; A-row mr=l15 ; jl = (mt>>1)*8 + ((mr>>2)<<1) + (mt&1)
  f16x8 wa[2][8], xa[2][2];
#pragma unroll
  for (int t=0;t<2;t++){
    const int mt  = w*2 + t;
    const int mr  = l15;
    const int jl  = (mt>>1)*8 + ((mr>>2)<<1) + (mt&1);
    const int row = (mr&3)*NHID + q*64 + jl;
#pragma unroll
    for (int kt=0;kt<8;kt++){
      const float* p = Wh + row*NHID + kt*32 + lhi*8;
      wa[t][kt] = cvt8(*(const f32x4*)p, *(const f32x4*)(p+4));
    }
#pragma unroll
    for (int kt=0;kt<2;kt++){
      const float* p = Wi + row*DIN + kt*32 + lhi*8;
      xa[t][kt] = cvt8(*(const f32x4*)p, *(const f32x4*)(p+4));
    }
  }

  // per-lane bias (acc init) and cell state; lane owns jl = w*8 + lhi*2 + t
  f32x4 binit0, binit1; float c[2];
#pragma unroll
  for (int t=0;t<2;t++){
    const int jl = w*8 + lhi*2 + t;
    f32x4 bv;
#pragma unroll
    for (int g=0; g<4; g++)
      bv[g] = bi[g*NHID + q*64 + jl] + bh[g*NHID + q*64 + jl];
    if (t==0) binit0 = bv; else binit1 = bv;
    c[t] = c0[(size_t)(grp*16+l15)*NHID + q*64 + jl];
  }

  // h0 -> hbuf[0]
  for (int i=tid; i<16*128; i+=NTHR){
    const int b = i>>7, cp = i&127;
    U32H2 pk;
    pk.h[0] = (_Float16)h0[(size_t)(grp*16+b)*NHID + cp*2];
    pk.h[1] = (_Float16)h0[(size_t)(grp*16+b)*NHID + cp*2 + 1];
    hbuf[0][i ^ ((b&7)<<2)] = pk.u;
  }
  __syncthreads();

  // x(0) -> acc init (bias folded), prefetch x(1)
  const float* xrow = x + (size_t)(grp*16 + l15) * (SEQ*DIN);
  f32x4 xp0,xp1,xp2,xp3;
  {
    const float* p = xrow + lhi*8;
    xp0 = *(const f32x4*)p;      xp1 = *(const f32x4*)(p+4);
    xp2 = *(const f32x4*)(p+32); xp3 = *(const f32x4*)(p+36);
  }
  f32x4 acc0, acc1;
  {
    f16x8 xb0 = cvt8(xp0, xp1), xb1 = cvt8(xp2, xp3);
    acc0 = MFMA16(xa[0][0], xb0, binit0);
    acc0 = MFMA16(xa[0][1], xb1, acc0);
    acc1 = MFMA16(xa[1][0], xb0, binit1);
    acc1 = MFMA16(xa[1][1], xb1, acc1);
  }
  {
    const float* p = xrow + DIN + lhi*8;
    xp0 = *(const f32x4*)p;      xp1 = *(const f32x4*)(p+4);
    xp2 = *(const f32x4*)(p+32); xp3 = *(const f32x4*)(p+36);
  }

  bool fastOK = false;

  for (int s=0; s<SEQ; s++){
    const unsigned int* hr = hbuf[s&1];
    unsigned int*       hw_= hbuf[(s+1)&1];
    const size_t pb = (size_t)((s&1)*NBLK + grp*4)*512;
    u64* Sb = slices + pb;
    u64* Fb = fastb  + pb;
    const unsigned tag = (unsigned)(s+1);

    // B-frags (swizzled, balanced banks)
    f16x8 hb[8];
#pragma unroll
    for (int kt=0;kt<8;kt++){
      const int word = (l15*128 + kt*16 + lhi*4) ^ ((l15&7)<<2);
      hb[kt] = *(const f16x8*)(hr + word);
    }
    // recurrent MFMAs, two 4-deep chains per acc
    f32x4 a0 = acc0, a1 = acc1;
    f32x4 b0 = {0.f,0.f,0.f,0.f}, b1 = {0.f,0.f,0.f,0.f};
#pragma unroll
    for (int kt=0;kt<4;kt++){
      a0 = MFMA16(wa[0][kt],   hb[kt],   a0);
      a1 = MFMA16(wa[1][kt],   hb[kt],   a1);
      b0 = MFMA16(wa[0][kt+4], hb[kt+4], b0);
      b1 = MFMA16(wa[1][kt+4], hb[kt+4], b1);
    }
    const f32x4 g0 = a0 + b0, g1 = a1 + b1;

    // pointwise in-register (r: 0=f,1=i,2=g,3=o)
    U32H2 pk;
    {
      const float f0 = sigm (g0[0]);
      const float i0 = sigm (g0[1]);
      const float gg0= tanh_f(g0[2]);
      const float o0 = sigm (g0[3]);
      c[0] = c[0]*f0 + i0*gg0;
      pk.h[0] = (_Float16)(tanh_f(c[0])*o0);
      const float f1 = sigm (g1[0]);
      const float i1 = sigm (g1[1]);
      const float gg1= tanh_f(g1[2]);
      const float o1 = sigm (g1[3]);
      c[1] = c[1]*f1 + i1*gg1;
      pk.h[1] = (_Float16)(tanh_f(c[1])*o1);
    }
    // publish BOTH paths (F first: it's the latency-critical one)
    {
      const u64 word = ((u64)tag << 32) | (u64)pk.u;
      ST_F(Fb + q*512 + w*64 + l, word);
      ASTORE(Sb + q*512 + w*64 + l, word);
      const int jp = w*4 + lhi;
      hw_[(l15*128 + q*32 + jp) ^ ((l15&7)<<2)] = pk.u;
    }
    // next-step input projection + x(s+2) prefetch (fills the wait shadow)
    {
      f16x8 xb0 = cvt8(xp0, xp1), xb1 = cvt8(xp2, xp3);
      acc0 = MFMA16(xa[0][0], xb0, binit0);
      acc0 = MFMA16(xa[0][1], xb1, acc0);
      acc1 = MFMA16(xa[1][0], xb0, binit1);
      acc1 = MFMA16(xa[1][1], xb1, acc1);
    }
    {
      const int sn = (s < SEQ-2) ? s+2 : SEQ-1;
      const float* p = xrow + sn*DIN + lhi*8;
      xp0 = *(const f32x4*)p;      xp1 = *(const f32x4*)(p+4);
      xp2 = *(const f32x4*)(p+32); xp3 = *(const f32x4*)(p+36);
    }

    // ---- exchange: poll 3 partners CONCURRENTLY ----
    const int qA=(q+1)&3, qB=(q+2)&3, qC=(q+3)&3;
    const int wo = w*64 + l;
    const u64* pFA = Fb + qA*512 + wo; const u64* pSA = Sb + qA*512 + wo;
    const u64* pFB = Fb + qB*512 + wo; const u64* pSB = Sb + qB*512 + wo;
    const u64* pFC = Fb + qC*512 + wo; const u64* pSC = Sb + qC*512 + wo;
    u64 vA=0, vB=0, vC=0;
    bool dA=false, dB=false, dC=false;

    if (s == 0){
      // bounded F-probe (learns placement), then guaranteed S-finish
      int tr = 0;
      while (!(dA&&dB&&dC) && tr < 1024){
        u64 fa=0, fb=0, fc=0;
        if(!dA) LD_F(fa, pFA);
        if(!dB) LD_F(fb, pFB);
        if(!dC) LD_F(fc, pFC);
        WAIT3(fa, fb, fc);
        if(!dA && (unsigned)(fa>>32)==tag){ vA=fa; dA=true; }
        if(!dB && (unsigned)(fb>>32)==tag){ vB=fb; dB=true; }
        if(!dC && (unsigned)(fc>>32)==tag){ vC=fc; dC=true; }
        ++tr;
      }
      fastOK = (bool)__all(dA && dB && dC);
      while (!(dA&&dB&&dC)){
        if(!dA){ u64 t2=ALOAD(pSA); if((unsigned)(t2>>32)==tag){ vA=t2; dA=true; } }
        if(!dB){ u64 t2=ALOAD(pSB); if((unsigned)(t2>>32)==tag){ vB=t2; dB=true; } }
        if(!dC){ u64 t2=ALOAD(pSC); if((unsigned)(t2>>32)==tag){ vC=t2; dC=true; } }
      }
    } else if (fastOK){
      int tr = 0;
      do {
        u64 fa=0, fb=0, fc=0;
        if(!dA) LD_F(fa, pFA);
        if(!dB) LD_F(fb, pFB);
        if(!dC) LD_F(fc, pFC);
        WAIT3(fa, fb, fc);
        if(!dA && (unsigned)(fa>>32)==tag){ vA=fa; dA=true; }
        if(!dB && (unsigned)(fb>>32)==tag){ vB=fb; dB=true; }
        if(!dC && (unsigned)(fc>>32)==tag){ vC=fc; dC=true; }
        if (((++tr) & 63) == 0){   // S backstop: spin can never hang
          if(!dA){ u64 t2=ALOAD(pSA); if((unsigned)(t2>>32)==tag){ vA=t2; dA=true; } }
          if(!dB){ u64 t2=ALOAD(pSB); if((unsigned)(t2>>32)==tag){ vB=t2; dB=true; } }
          if(!dC){ u64 t2=ALOAD(pSC); if((unsigned)(t2>>32)==tag){ vC=t2; dC=true; } }
        }
      } while (!(dA&&dB&&dC));
    } else {
      vA = ALOAD(pSA); vB = ALOAD(pSB); vC = ALOAD(pSC);
      while (((unsigned)(vA>>32)!=tag) | ((unsigned)(vB>>32)!=tag) |
             ((unsigned)(vC>>32)!=tag)){
        if((unsigned)(vA>>32)!=tag) vA = ALOAD(pSA);
        if((unsigned)(vB>>32)!=tag) vB = ALOAD(pSB);
        if((unsigned)(vC>>32)!=tag) vC = ALOAD(pSC);
      }
    }
    // partner colpairs -> hbuf (lane (w,l) owns colpair jp=w*4+lhi, b=l15)
    {
      const int jp = w*4 + lhi;
      hw_[(l15*128 + qA*32 + jp) ^ ((l15&7)<<2)] = (unsigned)vA;
      hw_[(l15*128 + qB*32 + jp) ^ ((l15&7)<<2)] = (unsigned)vB;
      hw_[(l15*128 + qC*32 + jp) ^ ((l15&7)<<2)] = (unsigned)vC;
    }
    __syncthreads();   // h(s+1) complete in hbuf; WAR guard across steps
  }

  // classifier: q==0 blocks hold full final h in hbuf[SEQ&1] = hbuf[0]
  if (q == 0 && tid < 160){
    const int b = tid/10, j = tid - b*10;
    const unsigned int* hf = hbuf[SEQ&1];
    float sum = bcls[j];
    for (int cp=0; cp<128; cp++){
      U32H2 v; v.u = hf[(b*128 + cp) ^ ((b&7)<<2)];
      sum += Wcls[j*NHID + cp*2]     * (float)v.h[0]
           + Wcls[j*NHID + cp*2 + 1] * (float)v.h[1];
    }
    out[(grp*16+b)*10 + j] = sum;
  }
}

extern "C" void kernel_launch(void* const* d_in, const int* in_sizes, int n_in,
                              void* d_out, int out_size, void* d_ws, size_t ws_size,
                              hipStream_t stream){
  const float* x    = (const float*)d_in[0];
  const float* h0   = (const float*)d_in[1];
  const float* c0   = (const float*)d_in[2];
  const float* Wi   = (const float*)d_in[3];
  const float* bi   = (const float*)d_in[4];
  const float* Wh   = (const float*)d_in[5];
  const float* bh   = (const float*)d_in[6];
  const float* Wcls = (const float*)d_in[7];
  const float* bcls = (const float*)d_in[8];

  char* ws = (char*)d_ws;
  u64* slices = (u64*)ws;                 // S: 2 x 64 x 512 u64 = 524288 B
  u64* fastb  = (u64*)(ws + 524288);      // F: 2 x 64 x 512 u64 = 524288 B

  // zero ALL tags (both paths) every launch; polled tags 1..1024 never match 0
  hipMemsetAsync(ws, 0, 2*524288, stream);
  hipLaunchKernelGGL(lstm_seq, dim3(NBLK), dim3(NTHR), 0, stream,
                     x, h0, c0, Wi, bi, Wh, bh, Wcls, bcls,
                     slices, fastb, (float*)d_out);
}

// Round 10
// 2345.580 us; speedup vs baseline: 6.0700x; 6.0700x over previous
//
#include <hip/hip_runtime.h>

#define SEQ   1024
#define DIN   64
#define NHID  256
#define NBLK  64
#define NTHR  512

typedef _Float16 f16x8 __attribute__((ext_vector_type(8)));
typedef float    f32x4 __attribute__((ext_vector_type(4)));
typedef unsigned long long u64;

#define MFMA16(a,b,c) __builtin_amdgcn_mfma_f32_16x16x32_f16((a),(b),(c),0,0,0)
#define ALOAD(p)    __hip_atomic_load((p), __ATOMIC_RELAXED, __HIP_MEMORY_SCOPE_AGENT)
#define ASTORE(p,v) __hip_atomic_store((p),(v), __ATOMIC_RELAXED, __HIP_MEMORY_SCOPE_AGENT)

__device__ __forceinline__ float sigm(float v){
  return __builtin_amdgcn_rcpf(1.f + __expf(-v));
}
__device__ __forceinline__ float tanh_f(float v){
  return 1.f - 2.f*__builtin_amdgcn_rcpf(__expf(2.f*v)+1.f);
}

__device__ __forceinline__ f16x8 cvt8(f32x4 a, f32x4 b){
  f16x8 r;
  r[0]=(_Float16)a[0]; r[1]=(_Float16)a[1]; r[2]=(_Float16)a[2]; r[3]=(_Float16)a[3];
  r[4]=(_Float16)b[0]; r[5]=(_Float16)b[1]; r[6]=(_Float16)b[2]; r[7]=(_Float16)b[3];
  return r;
}

union U32H2 { unsigned int u; _Float16 h[2]; unsigned short us[2]; };

// 64 blocks = 16 groups (16 batch rows) x 4 members (64 hidden cols).
// R4-proven exchange: tagged u64 {hi=s+1, lo=2xf16 colpair}, relaxed agent
// atomics, parity double-buffer, memset-0 per launch (tags 1..1024 never
// match stale/poison). R10 delta: the 3 partner polls are issued IMMEDIATELY
// after publish (pinned), checked only after the x-proj shadow, and retried
// CONCURRENTLY with exec-masked stale-only reloads (R4 discovered slow
// partners serially).
__global__ void __launch_bounds__(NTHR, 2)
lstm_seq(const float* __restrict__ x, const float* __restrict__ h0,
         const float* __restrict__ c0, const float* __restrict__ Wi,
         const float* __restrict__ bi, const float* __restrict__ Wh,
         const float* __restrict__ bh, const float* __restrict__ Wcls,
         const float* __restrict__ bcls,
         u64* __restrict__ slices, float* __restrict__ out)
{
  __shared__ __align__(16) unsigned int hbuf[2][16*128]; // word ^= (b&7)<<2

  const int bid = blockIdx.x;
  const int grp = bid & 15;          // batch group (16 rows)
  const int q   = bid >> 4;          // hidden quarter 0..3
  const int tid = threadIdx.x;
  const int w   = tid >> 6;          // wave 0..7
  const int l   = tid & 63;
  const int l15 = l & 15;
  const int lhi = l >> 4;

  // ---- A-frags: weights, register-resident f16, permuted rows ----
  // m-tile mt = w*2+t ; A-row mr=l15 ; jl = (mt>>1)*8 + ((mr>>2)<<1) + (mt&1)
  f16x8 wa[2][8], xa[2][2];
#pragma unroll
  for (int t=0;t<2;t++){
    const int mt  = w*2 + t;
    const int mr  = l15;
    const int jl  = (mt>>1)*8 + ((mr>>2)<<1) + (mt&1);
    const int row = (mr&3)*NHID + q*64 + jl;
#pragma unroll
    for (int kt=0;kt<8;kt++){
      const float* p = Wh + row*NHID + kt*32 + lhi*8;
      wa[t][kt] = cvt8(*(const f32x4*)p, *(const f32x4*)(p+4));
    }
#pragma unroll
    for (int kt=0;kt<2;kt++){
      const float* p = Wi + row*DIN + kt*32 + lhi*8;
      xa[t][kt] = cvt8(*(const f32x4*)p, *(const f32x4*)(p+4));
    }
  }

  // per-lane bias (acc init) and cell state; lane owns jl = w*8 + lhi*2 + t
  f32x4 binit0, binit1; float c[2];
#pragma unroll
  for (int t=0;t<2;t++){
    const int jl = w*8 + lhi*2 + t;
    f32x4 bv;
#pragma unroll
    for (int g=0; g<4; g++)
      bv[g] = bi[g*NHID + q*64 + jl] + bh[g*NHID + q*64 + jl];
    if (t==0) binit0 = bv; else binit1 = bv;
    c[t] = c0[(size_t)(grp*16+l15)*NHID + q*64 + jl];
  }

  // h0 -> hbuf[0]
  for (int i=tid; i<16*128; i+=NTHR){
    const int b = i>>7, cp = i&127;
    U32H2 pk;
    pk.h[0] = (_Float16)h0[(size_t)(grp*16+b)*NHID + cp*2];
    pk.h[1] = (_Float16)h0[(size_t)(grp*16+b)*NHID + cp*2 + 1];
    hbuf[0][i ^ ((b&7)<<2)] = pk.u;
  }
  __syncthreads();

  // x(0) -> acc init (bias folded), prefetch x(1)
  const float* xrow = x + (size_t)(grp*16 + l15) * (SEQ*DIN);
  f32x4 xp0,xp1,xp2,xp3;
  {
    const float* p = xrow + lhi*8;
    xp0 = *(const f32x4*)p;      xp1 = *(const f32x4*)(p+4);
    xp2 = *(const f32x4*)(p+32); xp3 = *(const f32x4*)(p+36);
  }
  f32x4 acc0, acc1;
  {
    f16x8 xb0 = cvt8(xp0, xp1), xb1 = cvt8(xp2, xp3);
    acc0 = MFMA16(xa[0][0], xb0, binit0);
    acc0 = MFMA16(xa[0][1], xb1, acc0);
    acc1 = MFMA16(xa[1][0], xb0, binit1);
    acc1 = MFMA16(xa[1][1], xb1, acc1);
  }
  {
    const float* p = xrow + DIN + lhi*8;
    xp0 = *(const f32x4*)p;      xp1 = *(const f32x4*)(p+4);
    xp2 = *(const f32x4*)(p+32); xp3 = *(const f32x4*)(p+36);
  }

  for (int s=0; s<SEQ; s++){
    const unsigned int* hr = hbuf[s&1];
    unsigned int*       hw_= hbuf[(s+1)&1];
    u64* base = slices + (size_t)((s&1)*NBLK + grp*4)*512;
    const unsigned tag = (unsigned)(s+1);

    // B-frags (swizzled, balanced banks)
    f16x8 hb[8];
#pragma unroll
    for (int kt=0;kt<8;kt++){
      const int word = (l15*128 + kt*16 + lhi*4) ^ ((l15&7)<<2);
      hb[kt] = *(const f16x8*)(hr + word);
    }
    // recurrent MFMAs, two 4-deep chains per acc
    f32x4 a0 = acc0, a1 = acc1;
    f32x4 b0 = {0.f,0.f,0.f,0.f}, b1 = {0.f,0.f,0.f,0.f};
#pragma unroll
    for (int kt=0;kt<4;kt++){
      a0 = MFMA16(wa[0][kt],   hb[kt],   a0);
      a1 = MFMA16(wa[1][kt],   hb[kt],   a1);
      b0 = MFMA16(wa[0][kt+4], hb[kt+4], b0);
      b1 = MFMA16(wa[1][kt+4], hb[kt+4], b1);
    }
    const f32x4 g0 = a0 + b0, g1 = a1 + b1;

    // pointwise in-register (r: 0=f,1=i,2=g,3=o)
    U32H2 pk;
    {
      const float f0 = sigm (g0[0]);
      const float i0 = sigm (g0[1]);
      const float gg0= tanh_f(g0[2]);
      const float o0 = sigm (g0[3]);
      c[0] = c[0]*f0 + i0*gg0;
      pk.h[0] = (_Float16)(tanh_f(c[0])*o0);
      const float f1 = sigm (g1[0]);
      const float i1 = sigm (g1[1]);
      const float gg1= tanh_f(g1[2]);
      const float o1 = sigm (g1[3]);
      c[1] = c[1]*f1 + i1*gg1;
      pk.h[1] = (_Float16)(tanh_f(c[1])*o1);
    }

    // ---- publish, then ISSUE all 3 partner polls immediately ----
    const int wo = w*64 + l;
    const int qA=(q+1)&3, qB=(q+2)&3, qC=(q+3)&3;
    const u64* pA = base + qA*512 + wo;
    const u64* pB = base + qB*512 + wo;
    const u64* pC = base + qC*512 + wo;
    ASTORE(base + q*512 + wo, ((u64)tag << 32) | (u64)pk.u);
    u64 vA = ALOAD(pA);
    u64 vB = ALOAD(pB);
    u64 vC = ALOAD(pC);
    __builtin_amdgcn_sched_barrier(0);   // pin: store+polls issued before shadow

    // ---- shadow: own hbuf write + next-step x-proj + x(s+2) prefetch ----
    {
      const int jp = w*4 + lhi;
      hw_[(l15*128 + q*32 + jp) ^ ((l15&7)<<2)] = pk.u;
    }
    {
      f16x8 xb0 = cvt8(xp0, xp1), xb1 = cvt8(xp2, xp3);
      acc0 = MFMA16(xa[0][0], xb0, binit0);
      acc0 = MFMA16(xa[0][1], xb1, acc0);
      acc1 = MFMA16(xa[1][0], xb0, binit1);
      acc1 = MFMA16(xa[1][1], xb1, acc1);
    }
    {
      const int sn = (s < SEQ-2) ? s+2 : SEQ-1;
      const float* p = xrow + sn*DIN + lhi*8;
      xp0 = *(const f32x4*)p;      xp1 = *(const f32x4*)(p+4);
      xp2 = *(const f32x4*)(p+32); xp3 = *(const f32x4*)(p+36);
    }

    // ---- check + concurrent stale-only retry (exec-masked per lane) ----
    bool dA = ((unsigned)(vA>>32) == tag);
    bool dB = ((unsigned)(vB>>32) == tag);
    bool dC = ((unsigned)(vC>>32) == tag);
    while (!(dA && dB && dC)){
      u64 nA, nB, nC;
      if (!dA) nA = ALOAD(pA);
      if (!dB) nB = ALOAD(pB);
      if (!dC) nC = ALOAD(pC);
      if (!dA && (unsigned)(nA>>32) == tag){ vA = nA; dA = true; }
      if (!dB && (unsigned)(nB>>32) == tag){ vB = nB; dB = true; }
      if (!dC && (unsigned)(nC>>32) == tag){ vC = nC; dC = true; }
    }
    // partner colpairs -> hbuf (lane (w,l) owns colpair jp=w*4+lhi, b=l15)
    {
      const int jp = w*4 + lhi;
      hw_[(l15*128 + qA*32 + jp) ^ ((l15&7)<<2)] = (unsigned)vA;
      hw_[(l15*128 + qB*32 + jp) ^ ((l15&7)<<2)] = (unsigned)vB;
      hw_[(l15*128 + qC*32 + jp) ^ ((l15&7)<<2)] = (unsigned)vC;
    }
    __syncthreads();   // h(s+1) complete in hbuf; WAR guard across steps
  }

  // classifier: q==0 blocks hold full final h in hbuf[SEQ&1] = hbuf[0]
  if (q == 0 && tid < 160){
    const int b = tid/10, j = tid - b*10;
    const unsigned int* hf = hbuf[SEQ&1];
    float sum = bcls[j];
    for (int cp=0; cp<128; cp++){
      U32H2 v; v.u = hf[(b*128 + cp) ^ ((b&7)<<2)];
      sum += Wcls[j*NHID + cp*2]     * (float)v.h[0]
           + Wcls[j*NHID + cp*2 + 1] * (float)v.h[1];
    }
    out[(grp*16+b)*10 + j] = sum;
  }
}

extern "C" void kernel_launch(void* const* d_in, const int* in_sizes, int n_in,
                              void* d_out, int out_size, void* d_ws, size_t ws_size,
                              hipStream_t stream){
  const float* x    = (const float*)d_in[0];
  const float* h0   = (const float*)d_in[1];
  const float* c0   = (const float*)d_in[2];
  const float* Wi   = (const float*)d_in[3];
  const float* bi   = (const float*)d_in[4];
  const float* Wh   = (const float*)d_in[5];
  const float* bh   = (const float*)d_in[6];
  const float* Wcls = (const float*)d_in[7];
  const float* bcls = (const float*)d_in[8];

  u64* slices = (u64*)d_ws;   // 2 parities x 64 slices x 512 u64 = 524288 B

  // zero all tags every launch: polled tags are 1..1024, 0 never matches
  hipMemsetAsync(slices, 0, 2*NBLK*512*sizeof(u64), stream);
  hipLaunchKernelGGL(lstm_seq, dim3(NBLK), dim3(NTHR), 0, stream,
                     x, h0, c0, Wi, bi, Wh, bh, Wcls, bcls,
                     slices, (float*)d_out);
}

// Round 11
// 2141.143 us; speedup vs baseline: 6.6496x; 1.0955x over previous
//
#include <hip/hip_runtime.h>

#define SEQ   1024
#define DIN   64
#define NHID  256
#define NBLK  64
#define NTHR  512

typedef _Float16 f16x8 __attribute__((ext_vector_type(8)));
typedef float    f32x4 __attribute__((ext_vector_type(4)));
typedef unsigned int u32;
typedef u32      u32x4 __attribute__((ext_vector_type(4)));
typedef unsigned long long u64;

#define MFMA16(a,b,c) __builtin_amdgcn_mfma_f32_16x16x32_f16((a),(b),(c),0,0,0)
#define ASTORE(p,v) __hip_atomic_store((p),(v), __ATOMIC_RELAXED, __HIP_MEMORY_SCOPE_AGENT)
// agent-visibility poll load: L1+L2 bypass (same coherence point as ASTORE)
#define PLOAD(d, b, O) \
  asm volatile("global_load_dwordx4 %0, %1, off offset:" #O " sc0 sc1" \
               : "=v"(d) : "v"(b) : "memory")
#define WAITBIND2(a,b) do{ \
  asm volatile("s_waitcnt vmcnt(0)" : "+v"(a), "+v"(b) :: "memory"); \
  __builtin_amdgcn_sched_barrier(0); }while(0)

__device__ __forceinline__ float sigm(float v){
  return __builtin_amdgcn_rcpf(1.f + __expf(-v));
}
__device__ __forceinline__ float tanh_f(float v){
  return 1.f - 2.f*__builtin_amdgcn_rcpf(__expf(2.f*v)+1.f);
}

__device__ __forceinline__ f16x8 cvt8(f32x4 a, f32x4 b){
  f16x8 r;
  r[0]=(_Float16)a[0]; r[1]=(_Float16)a[1]; r[2]=(_Float16)a[2]; r[3]=(_Float16)a[3];
  r[4]=(_Float16)b[0]; r[5]=(_Float16)b[1]; r[6]=(_Float16)b[2]; r[7]=(_Float16)b[3];
  return r;
}

union U32H2 { u32 u; _Float16 h[2]; unsigned short us[2]; };

// 64 blocks = 16 groups (16 batch rows) x 4 members (64 hidden cols).
// R4-proven tagged-u64 exchange (tag s+1, parity s&1, memset-0 per launch;
// relaxed agent atomics only — L2-scope paths refuted by R7/R9). R11 delta:
// slice layout is quarter-INTERLEAVED: word index = pos*4 + q (pos = w*64+l),
// so one lane's four quarter-words occupy one aligned 32B span. Publish = one
// scattered tagged-u64 store (latency-tolerant); poll = TWO adjacent coalesced
// dwordx4 loads returning ALL quarters' tags+payloads in one round trip.
// Each tagged u64 is written by one dwordx2-store and read within one 64B L3
// line -> no sub-word tearing. All-4 tag check keeps indexing static; own word
// is fresh-or-spin by the same protocol.
__global__ void __launch_bounds__(NTHR, 2)
lstm_seq(const float* __restrict__ x, const float* __restrict__ h0,
         const float* __restrict__ c0, const float* __restrict__ Wi,
         const float* __restrict__ bi, const float* __restrict__ Wh,
         const float* __restrict__ bh, const float* __restrict__ Wcls,
         const float* __restrict__ bcls,
         u64* __restrict__ slices, float* __restrict__ out)
{
  __shared__ __align__(16) u32 hbuf[2][16*128]; // word ^= (b&7)<<2

  const int bid = blockIdx.x;
  const int grp = bid & 15;          // batch group (16 rows)
  const int q   = bid >> 4;          // hidden quarter 0..3
  const int tid = threadIdx.x;
  const int w   = tid >> 6;          // wave 0..7
  const int l   = tid & 63;
  const int l15 = l & 15;
  const int lhi = l >> 4;

  // ---- A-frags: weights, register-resident f16, permuted rows ----
  // m-tile mt = w*2+t ; A-row mr=l15 ; jl = (mt>>1)*8 + ((mr>>2)<<1) + (mt&1)
  f16x8 wa[2][8], xa[2][2];
#pragma unroll
  for (int t=0;t<2;t++){
    const int mt  = w*2 + t;
    const int mr  = l15;
    const int jl  = (mt>>1)*8 + ((mr>>2)<<1) + (mt&1);
    const int row = (mr&3)*NHID + q*64 + jl;
#pragma unroll
    for (int kt=0;kt<8;kt++){
      const float* p = Wh + row*NHID + kt*32 + lhi*8;
      wa[t][kt] = cvt8(*(const f32x4*)p, *(const f32x4*)(p+4));
    }
#pragma unroll
    for (int kt=0;kt<2;kt++){
      const float* p = Wi + row*DIN + kt*32 + lhi*8;
      xa[t][kt] = cvt8(*(const f32x4*)p, *(const f32x4*)(p+4));
    }
  }

  // per-lane bias (acc init) and cell state; lane owns jl = w*8 + lhi*2 + t
  f32x4 binit0, binit1; float c[2];
#pragma unroll
  for (int t=0;t<2;t++){
    const int jl = w*8 + lhi*2 + t;
    f32x4 bv;
#pragma unroll
    for (int g=0; g<4; g++)
      bv[g] = bi[g*NHID + q*64 + jl] + bh[g*NHID + q*64 + jl];
    if (t==0) binit0 = bv; else binit1 = bv;
    c[t] = c0[(size_t)(grp*16+l15)*NHID + q*64 + jl];
  }

  // h0 -> hbuf[0]
  for (int i=tid; i<16*128; i+=NTHR){
    const int b = i>>7, cp = i&127;
    U32H2 pk;
    pk.h[0] = (_Float16)h0[(size_t)(grp*16+b)*NHID + cp*2];
    pk.h[1] = (_Float16)h0[(size_t)(grp*16+b)*NHID + cp*2 + 1];
    hbuf[0][i ^ ((b&7)<<2)] = pk.u;
  }
  __syncthreads();

  // x(0) -> acc init (bias folded), prefetch x(1)
  const float* xrow = x + (size_t)(grp*16 + l15) * (SEQ*DIN);
  f32x4 xp0,xp1,xp2,xp3;
  {
    const float* p = xrow + lhi*8;
    xp0 = *(const f32x4*)p;      xp1 = *(const f32x4*)(p+4);
    xp2 = *(const f32x4*)(p+32); xp3 = *(const f32x4*)(p+36);
  }
  f32x4 acc0, acc1;
  {
    f16x8 xb0 = cvt8(xp0, xp1), xb1 = cvt8(xp2, xp3);
    acc0 = MFMA16(xa[0][0], xb0, binit0);
    acc0 = MFMA16(xa[0][1], xb1, acc0);
    acc1 = MFMA16(xa[1][0], xb0, binit1);
    acc1 = MFMA16(xa[1][1], xb1, acc1);
  }
  {
    const float* p = xrow + DIN + lhi*8;
    xp0 = *(const f32x4*)p;      xp1 = *(const f32x4*)(p+4);
    xp2 = *(const f32x4*)(p+32); xp3 = *(const f32x4*)(p+36);
  }

  const int pos = w*64 + l;

  for (int s=0; s<SEQ; s++){
    const u32* hr = hbuf[s&1];
    u32*       hw_= hbuf[(s+1)&1];
    u64* base = slices + (size_t)((s&1)*16 + grp)*2048;  // [pos][quarter]
    const unsigned tag = (unsigned)(s+1);

    // B-frags (swizzled, balanced banks)
    f16x8 hb[8];
#pragma unroll
    for (int kt=0;kt<8;kt++){
      const int word = (l15*128 + kt*16 + lhi*4) ^ ((l15&7)<<2);
      hb[kt] = *(const f16x8*)(hr + word);
    }
    // recurrent MFMAs, two 4-deep chains per acc
    f32x4 a0 = acc0, a1 = acc1;
    f32x4 b0 = {0.f,0.f,0.f,0.f}, b1 = {0.f,0.f,0.f,0.f};
#pragma unroll
    for (int kt=0;kt<4;kt++){
      a0 = MFMA16(wa[0][kt],   hb[kt],   a0);
      a1 = MFMA16(wa[1][kt],   hb[kt],   a1);
      b0 = MFMA16(wa[0][kt+4], hb[kt+4], b0);
      b1 = MFMA16(wa[1][kt+4], hb[kt+4], b1);
    }
    const f32x4 g0 = a0 + b0, g1 = a1 + b1;

    // pointwise in-register (r: 0=f,1=i,2=g,3=o)
    U32H2 pk;
    {
      const float f0 = sigm (g0[0]);
      const float i0 = sigm (g0[1]);
      const float gg0= tanh_f(g0[2]);
      const float o0 = sigm (g0[3]);
      c[0] = c[0]*f0 + i0*gg0;
      pk.h[0] = (_Float16)(tanh_f(c[0])*o0);
      const float f1 = sigm (g1[0]);
      const float i1 = sigm (g1[1]);
      const float gg1= tanh_f(g1[2]);
      const float o1 = sigm (g1[3]);
      c[1] = c[1]*f1 + i1*gg1;
      pk.h[1] = (_Float16)(tanh_f(c[1])*o1);
    }

    // ---- publish own quarter-word (pinned: issue before shadow) ----
    ASTORE(base + pos*4 + q, ((u64)tag << 32) | (u64)pk.u);
    __builtin_amdgcn_sched_barrier(0);

    // ---- shadow: next-step x-proj + x(s+2) prefetch (R4's proven Δ) ----
    {
      f16x8 xb0 = cvt8(xp0, xp1), xb1 = cvt8(xp2, xp3);
      acc0 = MFMA16(xa[0][0], xb0, binit0);
      acc0 = MFMA16(xa[0][1], xb1, acc0);
      acc1 = MFMA16(xa[1][0], xb0, binit1);
      acc1 = MFMA16(xa[1][1], xb1, acc1);
    }
    {
      const int sn = (s < SEQ-2) ? s+2 : SEQ-1;
      const float* p = xrow + sn*DIN + lhi*8;
      xp0 = *(const f32x4*)p;      xp1 = *(const f32x4*)(p+4);
      xp2 = *(const f32x4*)(p+32); xp3 = *(const f32x4*)(p+36);
    }

    // ---- poll: ONE 32B span = all 4 quarters' tagged words ----
    const u64* pp = base + pos*4;
    u32x4 lo, hi;            // lo = {pl0,tg0,pl1,tg1}, hi = {pl2,tg2,pl3,tg3}
    PLOAD(lo, pp, 0); PLOAD(hi, pp, 16);
    WAITBIND2(lo, hi);
    while (lo[1]!=tag || lo[3]!=tag || hi[1]!=tag || hi[3]!=tag){
      PLOAD(lo, pp, 0); PLOAD(hi, pp, 16);
      WAITBIND2(lo, hi);
    }
    // all 4 quarters' colpairs -> hbuf (lane (w,l): colpair jp=w*4+lhi, b=l15)
    {
      const int jp = w*4 + lhi;
      hw_[(l15*128 +       jp) ^ ((l15&7)<<2)] = lo[0];
      hw_[(l15*128 +  32 + jp) ^ ((l15&7)<<2)] = lo[2];
      hw_[(l15*128 +  64 + jp) ^ ((l15&7)<<2)] = hi[0];
      hw_[(l15*128 +  96 + jp) ^ ((l15&7)<<2)] = hi[2];
    }
    __syncthreads();   // h(s+1) complete in hbuf; WAR guard across steps
  }

  // classifier: q==0 blocks hold full final h in hbuf[SEQ&1] = hbuf[0]
  if (q == 0 && tid < 160){
    const int b = tid/10, j = tid - b*10;
    const u32* hf = hbuf[SEQ&1];
    float sum = bcls[j];
    for (int cp=0; cp<128; cp++){
      U32H2 v; v.u = hf[(b*128 + cp) ^ ((b&7)<<2)];
      sum += Wcls[j*NHID + cp*2]     * (float)v.h[0]
           + Wcls[j*NHID + cp*2 + 1] * (float)v.h[1];
    }
    out[(grp*16+b)*10 + j] = sum;
  }
}

extern "C" void kernel_launch(void* const* d_in, const int* in_sizes, int n_in,
                              void* d_out, int out_size, void* d_ws, size_t ws_size,
                              hipStream_t stream){
  const float* x    = (const float*)d_in[0];
  const float* h0   = (const float*)d_in[1];
  const float* c0   = (const float*)d_in[2];
  const float* Wi   = (const float*)d_in[3];
  const float* bi   = (const float*)d_in[4];
  const float* Wh   = (const float*)d_in[5];
  const float* bh   = (const float*)d_in[6];
  const float* Wcls = (const float*)d_in[7];
  const float* bcls = (const float*)d_in[8];

  u64* slices = (u64*)d_ws;   // 2 parities x 16 groups x 512 pos x 4 quarters

  // zero all tags every launch: polled tags are 1..1024, 0 never matches
  hipMemsetAsync(slices, 0, (size_t)2*16*512*4*sizeof(u64), stream);
  hipLaunchKernelGGL(lstm_seq, dim3(NBLK), dim3(NTHR), 0, stream,
                     x, h0, c0, Wi, bi, Wh, bh, Wcls, bcls,
                     slices, (float*)d_out);
}